// Round 1
// baseline (98.870 us; speedup 1.0000x reference)
//
#include <hip/hip_runtime.h>
#include <math.h>

// Problem constants (fixed by the reference file)
#define N_POINTS   262144
#define NUM_FREQS  10
// INPUT_CH = 3 + 2*10*3 = 63; W is (1536, 63) row-major; per point we need
// rows 3v, 3v+1, 3v+2  -> 189 contiguous floats starting at W + v*189.

__global__ __launch_bounds__(256) void voxlin_kernel(
    const float* __restrict__ X,
    const float* __restrict__ W,
    const int*   __restrict__ row_ids,
    const int*   __restrict__ voxel_ids,
    float*       __restrict__ out)
{
    int i = blockIdx.x * 256 + threadIdx.x;
    if (i >= N_POINTS) return;

    const float x0 = X[3*i + 0];
    const float x1 = X[3*i + 1];
    const float x2 = X[3*i + 2];

    const int v = voxel_ids[i];
    const float* __restrict__ w0 = W + v * 189;   // row 3v
    const float* __restrict__ w1 = w0 + 63;       // row 3v+1
    const float* __restrict__ w2 = w0 + 126;      // row 3v+2

    // enc[0..2] = x
    float acc0 = x0*w0[0] + x1*w0[1] + x2*w0[2];
    float acc1 = x0*w1[0] + x1*w1[1] + x2*w1[2];
    float acc2 = x0*w2[0] + x1*w2[1] + x2*w2[2];

    // Base sin/cos at freq=2^0 (accurate), then double-angle recurrence.
    // 2^f * x is exact in fp32, so the angle matches the reference exactly;
    // amplitude/phase error from the recurrence is ~1e-4 after 9 doublings.
    float s0, c0, s1, c1, s2, c2;
    sincosf(x0, &s0, &c0);
    sincosf(x1, &s1, &c1);
    sincosf(x2, &s2, &c2);

    #pragma unroll
    for (int f = 0; f < NUM_FREQS; ++f) {
        const int b = 3 + 6*f;   // enc layout per freq: [s0 s1 s2 c0 c1 c2]
        acc0 += s0*w0[b] + s1*w0[b+1] + s2*w0[b+2]
              + c0*w0[b+3] + c1*w0[b+4] + c2*w0[b+5];
        acc1 += s0*w1[b] + s1*w1[b+1] + s2*w1[b+2]
              + c0*w1[b+3] + c1*w1[b+4] + c2*w1[b+5];
        acc2 += s0*w2[b] + s1*w2[b+1] + s2*w2[b+2]
              + c0*w2[b+3] + c1*w2[b+4] + c2*w2[b+5];
        if (f < NUM_FREQS - 1) {
            const float ns0 = 2.0f*s0*c0, nc0 = c0*c0 - s0*s0;
            const float ns1 = 2.0f*s1*c1, nc1 = c1*c1 - s1*s1;
            const float ns2 = 2.0f*s2*c2, nc2 = c2*c2 - s2*s2;
            s0 = ns0; c0 = nc0;
            s1 = ns1; c1 = nc1;
            s2 = ns2; c2 = nc2;
        }
    }

    const int r = row_ids[i];
    out[3*r + 0] = acc0;
    out[3*r + 1] = acc1;
    out[3*r + 2] = acc2;
}

extern "C" void kernel_launch(void* const* d_in, const int* in_sizes, int n_in,
                              void* d_out, int out_size, void* d_ws, size_t ws_size,
                              hipStream_t stream) {
    const float* X         = (const float*)d_in[0];
    const float* W         = (const float*)d_in[1];
    const int*   row_ids   = (const int*)d_in[2];
    const int*   voxel_ids = (const int*)d_in[3];
    float*       out       = (float*)d_out;

    const int threads = 256;
    const int blocks  = (N_POINTS + threads - 1) / threads;  // 1024
    voxlin_kernel<<<blocks, threads, 0, stream>>>(X, W, row_ids, voxel_ids, out);
}